// Round 8
// baseline (340.489 us; speedup 1.0000x reference)
//
#include <hip/hip_runtime.h>
#include <hip/hip_bf16.h>
#include <stdint.h>

typedef float f32x4 __attribute__((ext_vector_type(4)));
typedef float f32x16 __attribute__((ext_vector_type(16)));
typedef short s16x8 __attribute__((ext_vector_type(8)));
typedef unsigned int u32x2 __attribute__((ext_vector_type(2)));
typedef unsigned int u32x4 __attribute__((ext_vector_type(4)));

#define MDIM 8192
#define NDIM 4096
#define KDIM 4096
#define NKT  64   // K-tiles of 64 (conv granularity)

__device__ __forceinline__ unsigned pkbf(float lo, float hi) {
  unsigned short l = __builtin_bit_cast(unsigned short, __float2bfloat16(lo));
  unsigned short h = __builtin_bit_cast(unsigned short, __float2bfloat16(hi));
  return ((unsigned)h << 16) | (unsigned)l;
}

__device__ __forceinline__ void gload16(const void* g, void* l) {
  __builtin_amdgcn_global_load_lds((const __attribute__((address_space(1))) int*)g,
                                   (__attribute__((address_space(3))) int*)l, 16, 0, 0);
}

// Convert f32 row-major [rows][4096] -> bf16 32x32x16-MFMA fragment layout.
// Per (row-tile rt of 256, K-tile kt of 64): 32 KB = [h:2][ks2:2][f:8] x 1KB.
// Frag (h,ks2,f): rows f*32..+31, k = kt*64+h*32+ks2*16..+15; slot lane*16B
// holds row=lane&31, k-half=(lane>>5)*8, 8 contiguous bf16 (A/B operand
// layout of mfma_f32_32x32x16_bf16). ds_read_b128 = lane*16 conflict-free.
// Equivalently: k16-index K fragment f lives at byte K*8192 + f*1024 within
// the row-tile's 2MB panel (fully linear in K).
__global__ __launch_bounds__(256) void conv_tile(
    const float* __restrict__ X, const float* __restrict__ W,
    s16x8* __restrict__ wsA, s16x8* __restrict__ wsB) {
  __shared__ char lds[32768];
  const int b = blockIdx.x;
  const int tid = threadIdx.x;
  const float* src;
  s16x8* dst;
  int bi;
  if (b < 32 * NKT) { src = X; dst = wsA; bi = b; }
  else              { src = W; dst = wsB; bi = b - 32 * NKT; }
  const int rt = bi >> 6;
  const int kt = bi & 63;
  const int fr = tid >> 4;        // row sub-index (0..15)
  const int c4 = (tid & 15) * 4;  // k offset (f32 units) within K-tile
  const int h = c4 >> 5;
  const int ks2 = (c4 >> 4) & 1;
  const int lh = (c4 & 15) >> 3;  // k-half within 16-step
  const int e2 = (c4 & 7) * 2;    // byte offset of first elem
  #pragma unroll
  for (int f = 0; f < 16; ++f) {
    const int row = f * 16 + fr;
    f32x4 v = *(const f32x4*)(src + ((size_t)rt * 256 + row) * KDIM + kt * 64 + c4);
    u32x2 p = { pkbf(v[0], v[1]), pkbf(v[2], v[3]) };
    const int frag = (h * 2 + ks2) * 8 + (f >> 1);
    const int lane = lh * 32 + (f & 1) * 16 + fr;
    *(u32x2*)(lds + frag * 1024 + lane * 16 + e2) = p;
  }
  __syncthreads();
  const size_t ob = (size_t)bi * 2048;
  #pragma unroll
  for (int i = 0; i < 8; ++i)
    dst[ob + i * 256 + tid] = *(const s16x8*)(lds + (i * 256 + tid) * 16);
}

// 256x256x4096 bf16 GEMM, 32x32x16 MFMA. A staged via global_load_lds into a
// 4-slot x 16KB ring (k32 tiles); B fragments loaded DIRECTLY global->reg
// (ws is already fragment-layout; 1-phase ping-pong prefetch) — no B LDS
// traffic at all. One barrier per k16 phase, uniform vmcnt(4). Fused epilogue.
__global__ __launch_bounds__(512, 2) void gemm256(
    const s16x8* __restrict__ wsA, const s16x8* __restrict__ wsB,
    const float* __restrict__ bias, const float* __restrict__ Wg,
    const float* __restrict__ bg, float* __restrict__ out) {
  extern __shared__ char smem[];
  const int tid = threadIdx.x;
  const int lane = tid & 63;
  const int wid = tid >> 6;      // 0..7
  const int wr = wid >> 2;       // 0..1  (wave row: 128 rows)
  const int wc = wid & 3;        // 0..3  (wave col: 64 cols)
  const int c32 = lane & 31;
  const int q5 = lane >> 5;

  const int bid = blockIdx.x;
  const int swz = (bid & 7) * 64 + (bid >> 3);   // XCD-bijective (512 % 8 == 0)
  const int bm = swz >> 4;       // 0..31
  const int bn = swz & 15;       // 0..15

  const char* wsAb = (const char*)wsA + ((size_t)bm << 21);  // A panel (2MB)
  const char* wsBb = (const char*)wsB + ((size_t)bn << 21);  // B panel (2MB)

  // A ring: 4 slots x 16KB; tile t (k32) -> slot t&3; within: [h:2][f:8]x1KB.
  auto stageA = [&](int t, int slot) {
    const char* s = wsAb + ((size_t)t << 14) + (wid << 11) + (lane << 4);
    char* d = smem + (slot << 14) + (wid << 11);
    gload16(s, d);
    gload16(s + 1024, d + 1024);
  };

  const char* aRd = smem + (wr << 12) + (lane << 4);   // + slot*16K + h*8K + m*1K

  f32x16 acc[4][2];
  #pragma unroll
  for (int m = 0; m < 4; ++m)
    #pragma unroll
    for (int n = 0; n < 2; ++n) acc[m][n] = (f32x16)0.0f;

  s16x8 af[4], bE[2], bO[2];

  // B frag address for k16-index K, frag n of this wave (f = wc*2+n)
  const char* bAddr = wsBb + ((wc * 2) << 10) + (lane << 4);

  // Prologue: stage t0->slot0, t1->slot1 (4 gloads); load bE(K=0);
  // vmcnt(2) -> t0,t1 landed (bE may stay outstanding; compiler waits at use).
  stageA(0, 0);
  stageA(1, 1);
  #pragma unroll
  for (int n = 0; n < 2; ++n)
    bE[n] = *(const s16x8*)(bAddr + ((size_t)0 << 13) + (n << 10));
  asm volatile("s_waitcnt vmcnt(2)" ::: "memory");
  __builtin_amdgcn_s_barrier();

  // Per iteration t (k32 tile): two k16 phases.
  //  even: consume bE(K=2t), read A slot(t&3) h0, stage tile t+2, load bO(2t+1)
  //  odd : consume bO,       read A h1,            load bE(2t+2)
  // vmcnt(4) per phase: newest-4 = this phase's {stage x2 | -} + {Bload x2}
  //  -> prev-phase B landed; A-stage gets a 2-phase landing lead; ring slot
  //  overwrite is >=2 barriers after its last reader. Tail clamps write only
  //  never-read slots / load never-consumed B.
  #pragma clang loop unroll(disable)
  for (int t = 0; t < 128; ++t) {
    const int tn = (t + 2 < 128) ? t + 2 : 127;
    const size_t k1 = 2 * t + 1;
    const size_t k2 = (2 * t + 2 < 256) ? 2 * t + 2 : 255;
    const int slot = t & 3;
    // ---- even phase ----
    stageA(tn, (t + 2) & 3);
    #pragma unroll
    for (int n = 0; n < 2; ++n)
      bO[n] = *(const s16x8*)(bAddr + (k1 << 13) + (n << 10));
    #pragma unroll
    for (int m = 0; m < 4; ++m)
      af[m] = *(const s16x8*)(aRd + (slot << 14) + (m << 10));
    asm volatile("s_waitcnt vmcnt(4)" ::: "memory");
    __builtin_amdgcn_s_barrier();
    __builtin_amdgcn_s_setprio(1);
    #pragma unroll
    for (int m = 0; m < 4; ++m) {
      #pragma unroll
      for (int n = 0; n < 2; ++n)
        acc[m][n] = __builtin_amdgcn_mfma_f32_32x32x16_bf16(af[m], bE[n], acc[m][n], 0, 0, 0);
    }
    __builtin_amdgcn_s_setprio(0);
    // ---- odd phase ----
    #pragma unroll
    for (int n = 0; n < 2; ++n)
      bE[n] = *(const s16x8*)(bAddr + (k2 << 13) + (n << 10));
    #pragma unroll
    for (int m = 0; m < 4; ++m)
      af[m] = *(const s16x8*)(aRd + (slot << 14) + 8192 + (m << 10));
    asm volatile("s_waitcnt vmcnt(4)" ::: "memory");
    __builtin_amdgcn_s_barrier();
    __builtin_amdgcn_s_setprio(1);
    #pragma unroll
    for (int m = 0; m < 4; ++m) {
      #pragma unroll
      for (int n = 0; n < 2; ++n)
        acc[m][n] = __builtin_amdgcn_mfma_f32_32x32x16_bf16(af[m], bO[n], acc[m][n], 0, 0, 0);
    }
    __builtin_amdgcn_s_setprio(0);
  }

  // ---- drain, then fused group-linear epilogue ----
  asm volatile("s_waitcnt vmcnt(0)" ::: "memory");
  asm volatile("s_waitcnt lgkmcnt(0)" ::: "memory");
  __builtin_amdgcn_s_barrier();

  float bv[2];
  #pragma unroll
  for (int n = 0; n < 2; ++n) bv[n] = bias[bn * 256 + wc * 64 + n * 32 + c32];

  // y = acc + bias -> bf16 into sY fragment layout [Mf:8][Kc:16] x 1KB,
  // element (row,col): Mf=row>>5, Kc=col>>4, slot=((col>>3)&1)*32+(row&31),
  // byte = slot*16 + (col&7)*2.  (A-operand layout for the grouped GEMM.)
  {
    const int e2 = (c32 & 7) * 2;
    const int lh = (c32 >> 3) & 1;
    #pragma unroll
    for (int m = 0; m < 4; ++m) {
      const int Mf = wr * 4 + m;
      #pragma unroll
      for (int n = 0; n < 2; ++n) {
        const int Kc = wc * 4 + n * 2 + (c32 >> 4);
        char* base = smem + (Mf * 16 + Kc) * 1024 + lh * 512 + e2;
        #pragma unroll
        for (int r = 0; r < 16; ++r) {
          const int rl = (r & 3) + 8 * (r >> 2) + 4 * q5;
          const float y = acc[m][n][r] + bv[n];
          *(unsigned short*)(base + rl * 16) =
              __builtin_bit_cast(unsigned short, __float2bfloat16(y));
        }
      }
    }
  }
  asm volatile("s_waitcnt lgkmcnt(0)" ::: "memory");
  __builtin_amdgcn_s_barrier();

  // out_g = sY_g @ Wg[g]^T + bg ; wave (wr,wc): 128x64 out sub-tile,
  // K = its group's 128 y-cols (Kc = (wc>>1)*8 + ks). Wg direct from global
  // (L2-resident), converted in-reg to 32x32 B-fragments.
  const int g = bn * 2 + (wc >> 1);
  const float* wgb = Wg + (size_t)g * 16384;
  f32x16 acc2[4][2];
  #pragma unroll
  for (int m = 0; m < 4; ++m)
    #pragma unroll
    for (int n = 0; n < 2; ++n) acc2[m][n] = (f32x16)0.0f;

  #pragma unroll
  for (int ks = 0; ks < 8; ++ks) {
    const int Kc = (wc >> 1) * 8 + ks;
    s16x8 af2[4];
    #pragma unroll
    for (int m = 0; m < 4; ++m)
      af2[m] = *(const s16x8*)(smem + ((wr * 4 + m) * 16 + Kc) * 1024 + lane * 16);
    #pragma unroll
    for (int n = 0; n < 2; ++n) {
      const int ocl = (wc & 1) * 64 + n * 32 + c32;    // out col within group
      const float* wp = wgb + ocl * 128 + ks * 16 + q5 * 8;
      f32x4 w0 = *(const f32x4*)wp;
      f32x4 w1 = *(const f32x4*)(wp + 4);
      u32x4 pw = { pkbf(w0[0], w0[1]), pkbf(w0[2], w0[3]),
                   pkbf(w1[0], w1[1]), pkbf(w1[2], w1[3]) };
      const s16x8 bfw = __builtin_bit_cast(s16x8, pw);
      #pragma unroll
      for (int m = 0; m < 4; ++m)
        acc2[m][n] = __builtin_amdgcn_mfma_f32_32x32x16_bf16(af2[m], bfw, acc2[m][n], 0, 0, 0);
    }
  }

  float bgv[2];
  #pragma unroll
  for (int n = 0; n < 2; ++n) bgv[n] = bg[bn * 256 + wc * 64 + n * 32 + c32];

  #pragma unroll
  for (int m = 0; m < 4; ++m) {
    #pragma unroll
    for (int n = 0; n < 2; ++n) {
      const int col = bn * 256 + wc * 64 + n * 32 + c32;
      #pragma unroll
      for (int r = 0; r < 16; ++r) {
        const size_t row = (size_t)bm * 256 + wr * 128 + m * 32
                         + (r & 3) + 8 * (r >> 2) + 4 * q5;
        out[row * NDIM + col] = acc2[m][n][r] + bgv[n];
      }
    }
  }
}

extern "C" void kernel_launch(void* const* d_in, const int* in_sizes, int n_in,
                              void* d_out, int out_size, void* d_ws, size_t ws_size,
                              hipStream_t stream) {
  const float* X    = (const float*)d_in[0];
  const float* W    = (const float*)d_in[1];
  const float* bias = (const float*)d_in[2];
  const float* Wg   = (const float*)d_in[3];
  const float* bg   = (const float*)d_in[4];
  float* out = (float*)d_out;

  s16x8* wsA = (s16x8*)d_ws;                       // 64 MB
  s16x8* wsB = wsA + ((size_t)MDIM * KDIM / 8);    // 32 MB

  hipFuncSetAttribute(reinterpret_cast<const void*>(gemm256),
                      hipFuncAttributeMaxDynamicSharedMemorySize, 131072);

  conv_tile<<<dim3(3072), dim3(256), 0, stream>>>(X, W, wsA, wsB);
  gemm256<<<dim3(512), dim3(512), 131072, stream>>>(wsA, wsB, bias, Wg, bg, out);
}

// Round 9
// 313.863 us; speedup vs baseline: 1.0848x; 1.0848x over previous
//
#include <hip/hip_runtime.h>
#include <hip/hip_bf16.h>
#include <stdint.h>

typedef float f32x4 __attribute__((ext_vector_type(4)));
typedef float f32x16 __attribute__((ext_vector_type(16)));
typedef short s16x8 __attribute__((ext_vector_type(8)));
typedef unsigned int u32x2 __attribute__((ext_vector_type(2)));
typedef unsigned int u32x4 __attribute__((ext_vector_type(4)));

#define MDIM 8192
#define NDIM 4096
#define KDIM 4096
#define NKT  64   // K-tiles of 64 (conv granularity)

__device__ __forceinline__ unsigned pkbf(float lo, float hi) {
  unsigned short l = __builtin_bit_cast(unsigned short, __float2bfloat16(lo));
  unsigned short h = __builtin_bit_cast(unsigned short, __float2bfloat16(hi));
  return ((unsigned)h << 16) | (unsigned)l;
}

__device__ __forceinline__ void gload16(const void* g, void* l) {
  __builtin_amdgcn_global_load_lds((const __attribute__((address_space(1))) int*)g,
                                   (__attribute__((address_space(3))) int*)l, 16, 0, 0);
}

// Convert f32 row-major [rows][4096] -> bf16 32x32x16-MFMA fragment layout.
// Per (row-tile rt of 256, K-tile kt of 64): 32 KB = [h:2][ks2:2][f:8] x 1KB.
// Frag (h,ks2,f): rows f*32..+31, k = kt*64+h*32+ks2*16..+15; slot lane*16B
// holds row=lane&31, k-half=(lane>>5)*8, 8 contiguous bf16 (A/B operand
// layout of mfma_f32_32x32x16_bf16). ds_read_b128 = lane*16 conflict-free.
// Equivalently: k16-index K fragment f lives at byte K*8192 + f*1024 within
// the row-tile's 2MB panel; a k32 tile t is the linear 16KB at t*16384.
__global__ __launch_bounds__(256) void conv_tile(
    const float* __restrict__ X, const float* __restrict__ W,
    s16x8* __restrict__ wsA, s16x8* __restrict__ wsB) {
  __shared__ char lds[32768];
  const int b = blockIdx.x;
  const int tid = threadIdx.x;
  const float* src;
  s16x8* dst;
  int bi;
  if (b < 32 * NKT) { src = X; dst = wsA; bi = b; }
  else              { src = W; dst = wsB; bi = b - 32 * NKT; }
  const int rt = bi >> 6;
  const int kt = bi & 63;
  const int fr = tid >> 4;        // row sub-index (0..15)
  const int c4 = (tid & 15) * 4;  // k offset (f32 units) within K-tile
  const int h = c4 >> 5;
  const int ks2 = (c4 >> 4) & 1;
  const int lh = (c4 & 15) >> 3;  // k-half within 16-step
  const int e2 = (c4 & 7) * 2;    // byte offset of first elem
  #pragma unroll
  for (int f = 0; f < 16; ++f) {
    const int row = f * 16 + fr;
    f32x4 v = *(const f32x4*)(src + ((size_t)rt * 256 + row) * KDIM + kt * 64 + c4);
    u32x2 p = { pkbf(v[0], v[1]), pkbf(v[2], v[3]) };
    const int frag = (h * 2 + ks2) * 8 + (f >> 1);
    const int lane = lh * 32 + (f & 1) * 16 + fr;
    *(u32x2*)(lds + frag * 1024 + lane * 16 + e2) = p;
  }
  __syncthreads();
  const size_t ob = (size_t)bi * 2048;
  #pragma unroll
  for (int i = 0; i < 8; ++i)
    dst[ob + i * 256 + tid] = *(const s16x8*)(lds + (i * 256 + tid) * 16);
}

// 256x256x4096 bf16 GEMM, 32x32x16 MFMA. A+B staged via global_load_lds into
// a 4-slot x 32KB ring (k32 sections). ONE barrier per section; the two k16
// phases inside a section FREE-RUN (no barrier), so different waves' ds_reads
// overlap sibling waves' MFMAs instead of serializing CU-wide. Fused epilogue.
__global__ __launch_bounds__(512, 2) void gemm256(
    const s16x8* __restrict__ wsA, const s16x8* __restrict__ wsB,
    const float* __restrict__ bias, const float* __restrict__ Wg,
    const float* __restrict__ bg, float* __restrict__ out) {
  extern __shared__ char smem[];
  const int tid = threadIdx.x;
  const int lane = tid & 63;
  const int wid = tid >> 6;      // 0..7
  const int wr = wid >> 2;       // 0..1  (wave row: 128 rows)
  const int wc = wid & 3;        // 0..3  (wave col: 64 cols)
  const int c32 = lane & 31;
  const int q5 = lane >> 5;

  const int bid = blockIdx.x;
  const int swz = (bid & 7) * 64 + (bid >> 3);   // XCD-bijective (512 % 8 == 0)
  const int bm = swz >> 4;       // 0..31
  const int bn = swz & 15;       // 0..15

  const char* wsAb = (const char*)wsA + ((size_t)bm << 21);  // A panel (2MB)
  const char* wsBb = (const char*)wsB + ((size_t)bn << 21);  // B panel (2MB)

  // Ring slot (32KB): A k32-tile at +0 (16KB, [ks2:2][f:8]x1KB), B at +16384.
  // Stage = 4 gload16/thread (2 A + 2 B), fully linear.
  auto stage = [&](int t, int slot) {
    const char* sa = wsAb + ((size_t)t << 14) + (wid << 11) + (lane << 4);
    const char* sb = wsBb + ((size_t)t << 14) + (wid << 11) + (lane << 4);
    char* d = smem + (slot << 15) + (wid << 11);
    gload16(sa, d);
    gload16(sa + 1024, d + 1024);
    gload16(sb, d + 16384);
    gload16(sb + 1024, d + 16384 + 1024);
  };

  const char* aRd = smem + ((wr * 4) << 10) + (lane << 4);           // + so + ks*8192 + m*1K
  const char* bRd = smem + 16384 + ((wc * 2) << 10) + (lane << 4);   // + so + ks*8192 + n*1K

  f32x16 acc[4][2];
  #pragma unroll
  for (int m = 0; m < 4; ++m)
    #pragma unroll
    for (int n = 0; n < 2; ++n) acc[m][n] = (f32x16)0.0f;

  s16x8 af[4], bfr[2];

  // Prologue: stage t0->slot0, t1->slot1 (8 gloads).
  stage(0, 0);
  stage(1, 1);

  // Section t: stage(t+2)->slot (t+2)&3 [safe: last readers ran in section
  // t-2, all waves crossed barrier t-1 before any wave reaches here];
  // vmcnt(8) [outstanding = {t+1,t+2} stages] -> tile t landed; barrier
  // publishes. Then 2 free-run k16 phases: ds_read 4A+2B, lgkm(0)+SB(0)
  // (rule #18), 8 MFMA under setprio. No closing barrier.
  #pragma clang loop unroll(disable)
  for (int t = 0; t < 128; ++t) {
    const int tn = (t + 2 < 128) ? t + 2 : 127;   // clamped restage hits a
    stage(tn, (t + 2) & 3);                       // never-again-read slot
    asm volatile("s_waitcnt vmcnt(8)" ::: "memory");
    __builtin_amdgcn_s_barrier();
    const int so = (t & 3) << 15;
    #pragma unroll
    for (int ks = 0; ks < 2; ++ks) {
      #pragma unroll
      for (int n = 0; n < 2; ++n)
        bfr[n] = *(const s16x8*)(bRd + so + ks * 8192 + (n << 10));
      #pragma unroll
      for (int m = 0; m < 4; ++m)
        af[m] = *(const s16x8*)(aRd + so + ks * 8192 + (m << 10));
      asm volatile("s_waitcnt lgkmcnt(0)" ::: "memory");
      __builtin_amdgcn_sched_barrier(0);
      __builtin_amdgcn_s_setprio(1);
      #pragma unroll
      for (int m = 0; m < 4; ++m) {
        #pragma unroll
        for (int n = 0; n < 2; ++n)
          acc[m][n] = __builtin_amdgcn_mfma_f32_32x32x16_bf16(af[m], bfr[n], acc[m][n], 0, 0, 0);
      }
      __builtin_amdgcn_s_setprio(0);
    }
  }

  // ---- drain, then fused group-linear epilogue ----
  asm volatile("s_waitcnt vmcnt(0)" ::: "memory");
  asm volatile("s_waitcnt lgkmcnt(0)" ::: "memory");
  __builtin_amdgcn_s_barrier();

  float bv[2];
  #pragma unroll
  for (int n = 0; n < 2; ++n) bv[n] = bias[bn * 256 + wc * 64 + n * 32 + c32];

  // y = acc + bias -> bf16 into sY fragment layout [Mf:8][Kc:16] x 1KB,
  // element (row,col): Mf=row>>5, Kc=col>>4, slot=((col>>3)&1)*32+(row&31),
  // byte = slot*16 + (col&7)*2.  (A-operand layout for the grouped GEMM.)
  {
    const int e2 = (c32 & 7) * 2;
    const int lh = (c32 >> 3) & 1;
    #pragma unroll
    for (int m = 0; m < 4; ++m) {
      const int Mf = wr * 4 + m;
      #pragma unroll
      for (int n = 0; n < 2; ++n) {
        const int Kc = wc * 4 + n * 2 + (c32 >> 4);
        char* base = smem + (Mf * 16 + Kc) * 1024 + lh * 512 + e2;
        #pragma unroll
        for (int r = 0; r < 16; ++r) {
          const int rl = (r & 3) + 8 * (r >> 2) + 4 * q5;
          const float y = acc[m][n][r] + bv[n];
          *(unsigned short*)(base + rl * 16) =
              __builtin_bit_cast(unsigned short, __float2bfloat16(y));
        }
      }
    }
  }
  asm volatile("s_waitcnt lgkmcnt(0)" ::: "memory");
  __builtin_amdgcn_s_barrier();

  // out_g = sY_g @ Wg[g]^T + bg ; wave (wr,wc): 128x64 out sub-tile,
  // K = its group's 128 y-cols (Kc = (wc>>1)*8 + ks). Wg direct from global
  // (L2-resident), converted in-reg to 32x32 B-fragments.
  const int g = bn * 2 + (wc >> 1);
  const float* wgb = Wg + (size_t)g * 16384;
  f32x16 acc2[4][2];
  #pragma unroll
  for (int m = 0; m < 4; ++m)
    #pragma unroll
    for (int n = 0; n < 2; ++n) acc2[m][n] = (f32x16)0.0f;

  #pragma unroll
  for (int ks = 0; ks < 8; ++ks) {
    const int Kc = (wc >> 1) * 8 + ks;
    s16x8 af2[4];
    #pragma unroll
    for (int m = 0; m < 4; ++m)
      af2[m] = *(const s16x8*)(smem + ((wr * 4 + m) * 16 + Kc) * 1024 + lane * 16);
    #pragma unroll
    for (int n = 0; n < 2; ++n) {
      const int ocl = (wc & 1) * 64 + n * 32 + c32;    // out col within group
      const float* wp = wgb + ocl * 128 + ks * 16 + q5 * 8;
      f32x4 w0 = *(const f32x4*)wp;
      f32x4 w1 = *(const f32x4*)(wp + 4);
      u32x4 pw = { pkbf(w0[0], w0[1]), pkbf(w0[2], w0[3]),
                   pkbf(w1[0], w1[1]), pkbf(w1[2], w1[3]) };
      const s16x8 bfw = __builtin_bit_cast(s16x8, pw);
      #pragma unroll
      for (int m = 0; m < 4; ++m)
        acc2[m][n] = __builtin_amdgcn_mfma_f32_32x32x16_bf16(af2[m], bfw, acc2[m][n], 0, 0, 0);
    }
  }

  float bgv[2];
  #pragma unroll
  for (int n = 0; n < 2; ++n) bgv[n] = bg[bn * 256 + wc * 64 + n * 32 + c32];

  #pragma unroll
  for (int m = 0; m < 4; ++m) {
    #pragma unroll
    for (int n = 0; n < 2; ++n) {
      const int col = bn * 256 + wc * 64 + n * 32 + c32;
      #pragma unroll
      for (int r = 0; r < 16; ++r) {
        const size_t row = (size_t)bm * 256 + wr * 128 + m * 32
                         + (r & 3) + 8 * (r >> 2) + 4 * q5;
        out[row * NDIM + col] = acc2[m][n][r] + bgv[n];
      }
    }
  }
}

extern "C" void kernel_launch(void* const* d_in, const int* in_sizes, int n_in,
                              void* d_out, int out_size, void* d_ws, size_t ws_size,
                              hipStream_t stream) {
  const float* X    = (const float*)d_in[0];
  const float* W    = (const float*)d_in[1];
  const float* bias = (const float*)d_in[2];
  const float* Wg   = (const float*)d_in[3];
  const float* bg   = (const float*)d_in[4];
  float* out = (float*)d_out;

  s16x8* wsA = (s16x8*)d_ws;                       // 64 MB
  s16x8* wsB = wsA + ((size_t)MDIM * KDIM / 8);    // 32 MB

  hipFuncSetAttribute(reinterpret_cast<const void*>(gemm256),
                      hipFuncAttributeMaxDynamicSharedMemorySize, 131072);

  conv_tile<<<dim3(3072), dim3(256), 0, stream>>>(X, W, wsA, wsB);
  gemm256<<<dim3(512), dim3(512), 131072, stream>>>(wsA, wsB, bias, Wg, bg, out);
}